// Round 16
// baseline (16097.211 us; speedup 1.0000x reference)
//
#include <hip/hip_runtime.h>
#include <stdint.h>

typedef __attribute__((ext_vector_type(4))) float f32x4;
typedef __attribute__((ext_vector_type(4))) int   i32x4;
typedef __attribute__((ext_vector_type(8))) char  s8x8;
typedef __attribute__((ext_vector_type(16))) char s8x16;
typedef unsigned short u16;

constexpr int    Tn  = 8;
constexpr int    Nn  = 512;
constexpr int    Cn  = 768;
constexpr int    Dn  = 64;
constexpr int    BHn = 96;
constexpr int    BNn = 4096;
constexpr int    C3n = 2304;
constexpr size_t BHND = 3145728;     // B*H*N*D
constexpr size_t BHNN = 25165824;    // B*H*N*N
constexpr size_t BNC  = 3145728;     // B*N*C

// ---- all buffers produced-before-consumed each call (no persistent state) ----
__device__ __attribute__((aligned(16))) int8_t g_A1[(size_t)Tn * BHND * 2];  // [t][bh][n][128]
__device__ __attribute__((aligned(16))) int8_t g_B1[(size_t)Tn * BHND * 2];
__device__ __attribute__((aligned(16))) short  g_S16[(size_t)Tn * BHNN];     // [t][bh][n][n]
__device__ __attribute__((aligned(16))) int8_t g_v8 [(size_t)Tn * BHND];     // [t][bh][n][d]
__device__ __attribute__((aligned(16))) int8_t g_vd8[(size_t)Tn * BHND];     // [t][bh][n][d]
__device__ __attribute__((aligned(16))) int8_t g_vT[(size_t)Tn * BHn * Dn * 1024]; // [t][bh][d][1024]
__device__ __attribute__((aligned(16))) int8_t g_sifa8[(size_t)Tn * BHNN];   // sif acc after step t
__device__ __attribute__((aligned(16))) int8_t g_spk8[(size_t)Tn * BHNN];    // sif spike at step t
__device__ __attribute__((aligned(16))) int8_t g_osp8i[(size_t)BNn * Tn * Cn]; // [bn*8+t][C]

static __device__ __forceinline__ void st2i8(int8_t* p, int v0, int v1) {
    *(short*)p = (short)((v0 & 0xff) | (v1 << 8));
}

// symmetric IF neuron step (pos_max=7, neg_min=-8)
static __device__ __forceinline__ float if_sym(float x, float& q, int& a) {
    float q2 = q + x;
    bool pos = ((q2 - 1.0f) >= 0.0f) && (a < 7);
    bool neg = (q2 < 0.0f) && (a > -8);
    float out = pos ? 1.0f : (neg ? -1.0f : 0.0f);
    q = q2 - out;
    a += (int)out;
    return out;
}

// ---------------- qkv GEMM (frozen fp32 chain) + FUSED q/k/v IF epilogue ----
// __launch_bounds__(256, 8): request 8 blocks/CU residency (VGPR 56 <= 64, no
// codegen pressure) — occupancy experiment for the 43%-resident mystery.
__global__ __launch_bounds__(256, 8) void gemm_qkv_fused(
    const float* __restrict__ X, const float* __restrict__ B)
{
    __shared__ __align__(16) float As[16][132];   // 128+4
    __shared__ __align__(16) float Bs[16][100];   // 96+4
    const int tid = threadIdx.x;
    const int m0 = blockIdx.y * 128;
    const int j0 = blockIdx.x * 96;
    const int ty = tid >> 4, tx = tid & 15;

    float acc[8][6];
#pragma unroll
    for (int i = 0; i < 8; ++i)
#pragma unroll
        for (int j = 0; j < 6; ++j) acc[i][j] = 0.0f;

    for (int k0 = 0; k0 < Cn; k0 += 16) {
#pragma unroll
        for (int u = 0; u < 2; ++u) {
            int f = tid + u * 256;
            int row = f >> 2;
            int c4 = (f & 3) * 4;
            int m = m0 + row;
            int t = m & 7, bn = m >> 3;
            int b = bn >> 9, n = bn & 511;
            const float* xr = X + ((size_t)((t * 8 + b) * Nn + n)) * Cn;
            float4 av = *(const float4*)(xr + k0 + c4);
            As[c4 + 0][row] = av.x; As[c4 + 1][row] = av.y;
            As[c4 + 2][row] = av.z; As[c4 + 3][row] = av.w;
        }
#pragma unroll
        for (int u = 0; u < 3; ++u) {
            int f = tid + u * 256;
            int row = f >> 3;
            int c2 = (f & 7) * 2;
            float2 bv = *(const float2*)(B + (size_t)(j0 + row) * Cn + k0 + c2);
            Bs[c2][row] = bv.x; Bs[c2 + 1][row] = bv.y;
        }
        __syncthreads();
#pragma unroll
        for (int k = 0; k < 16; ++k) {
            alignas(16) float a[8];
            alignas(8)  float b[6];
            *(float4*)(a)     = *(const float4*)&As[k][ty * 8];
            *(float4*)(a + 4) = *(const float4*)&As[k][ty * 8 + 4];
#pragma unroll
            for (int u = 0; u < 3; ++u) {
                float2 t = *(const float2*)&Bs[k][tx * 2 + 32 * u];
                b[2 * u] = t.x; b[2 * u + 1] = t.y;
            }
#pragma unroll
            for (int i = 0; i < 8; ++i)
#pragma unroll
                for (int j = 0; j < 6; ++j)
                    acc[i][j] = fmaf(a[i], b[j], acc[i][j]);
        }
        __syncthreads();
    }

    // fused IF epilogue: 6 independent 8-step chains per thread
    const int type = (j0 >= 1536) ? 2 : ((j0 >= 768) ? 1 : 0);
    const int bn = (m0 + ty * 8) >> 3;
    const int b = bn >> 9, n = bn & 511;
#pragma unroll
    for (int u = 0; u < 3; ++u) {
        int c  = j0 + 32 * u + tx * 2;
        int cl = c - type * 768;
        int h = cl >> 6, d = cl & 63;
        int bh = b * 12 + h;
        float q0 = 0.5f, q1 = 0.5f;
        int   a0 = 0,    a1 = 0;
#pragma unroll
        for (int t = 0; t < Tn; ++t) {
            float o0 = if_sym(acc[t][2 * u],     q0, a0);
            float o1 = if_sym(acc[t][2 * u + 1], q1, a1);
            if (type == 0) {
                size_t p = (((size_t)t * BHn + bh) * Nn + n) * 128 + d;
                st2i8(&g_A1[p],      a0,      a1);
                st2i8(&g_A1[p + 64], (int)o0, (int)o1);
            } else if (type == 1) {
                size_t p = (((size_t)t * BHn + bh) * Nn + n) * 128 + d;
                st2i8(&g_B1[p],      (int)o0,      (int)o1);
                st2i8(&g_B1[p + 64], a0 - (int)o0, a1 - (int)o1);
            } else {
                size_t p = (size_t)t * BHND + ((size_t)bh * Nn + n) * 64 + d;
                st2i8(&g_v8[p],  (int)o0,      (int)o1);
                st2i8(&g_vd8[p], a0 - (int)o0, a1 - (int)o1);
            }
        }
    }
}

// ---------------- build vT[t][bh][d][1024] (LDS-tiled transpose) ------------
__global__ __launch_bounds__(256) void vT_build() {
    int bh = blockIdx.x % BHn;
    int t  = blockIdx.x / BHn;
    const int8_t* src0 = g_v8  + (size_t)t * BHND + (size_t)bh * Nn * Dn;
    const int8_t* src1 = g_vd8 + (size_t)t * BHND + (size_t)bh * Nn * Dn;
    int8_t* dst = g_vT + ((size_t)t * BHn + bh) * Dn * 1024;
    __shared__ __align__(16) int8_t tile[64][80];
    int tid = threadIdx.x;

    for (int s = 0; s < 2; ++s) {
        const int8_t* src = s ? src1 : src0;
        int koff = s * 512;
        for (int nb = 0; nb < Nn; nb += 64) {
            {
                int n  = tid >> 2;
                int d0 = (tid & 3) * 16;
                s8x16 v = *(const s8x16*)(src + (size_t)(nb + n) * Dn + d0);
                *(s8x16*)&tile[n][d0] = v;
            }
            __syncthreads();
            {
                int d  = tid >> 2;
                int n0 = (tid & 3) * 16;
                s8x16 o;
#pragma unroll
                for (int j = 0; j < 16; ++j) o[j] = tile[n0 + j][d];
                *(s8x16*)(dst + (size_t)d * 1024 + koff + nb + n0) = o;
            }
            __syncthreads();
        }
    }
}

// ---------------- attn logits for ALL t (i8 MFMA, exact int32) --------------
__global__ __launch_bounds__(256) void gemm_attn_all() {
    int t = blockIdx.z;
    int bh = blockIdx.y;
    int tm = blockIdx.x >> 3, tn = blockIdx.x & 7;
    int wave = threadIdx.x >> 6, lane = threadIdx.x & 63;
    int wr = wave >> 1, wc = wave & 1;
    int row0 = tm * 64 + wr * 32, col0 = tn * 64 + wc * 32;
    const int8_t* Ab = g_A1 + ((size_t)t * BHn + bh) * Nn * 128;
    const int8_t* Bb = g_B1 + ((size_t)t * BHn + bh) * Nn * 128;
    int lr = lane & 15, kg = (lane >> 4) * 16;
    i32x4 acc[2][2] = {};
#pragma unroll
    for (int kk = 0; kk < 128; kk += 64) {
        i32x4 a0 = *(const i32x4*)(Ab + (size_t)(row0 + lr) * 128 + kk + kg);
        i32x4 a1 = *(const i32x4*)(Ab + (size_t)(row0 + 16 + lr) * 128 + kk + kg);
        i32x4 b0 = *(const i32x4*)(Bb + (size_t)(col0 + lr) * 128 + kk + kg);
        i32x4 b1 = *(const i32x4*)(Bb + (size_t)(col0 + 16 + lr) * 128 + kk + kg);
        acc[0][0] = __builtin_amdgcn_mfma_i32_16x16x64_i8(a0, b0, acc[0][0], 0, 0, 0);
        acc[0][1] = __builtin_amdgcn_mfma_i32_16x16x64_i8(a0, b1, acc[0][1], 0, 0, 0);
        acc[1][0] = __builtin_amdgcn_mfma_i32_16x16x64_i8(a1, b0, acc[1][0], 0, 0, 0);
        acc[1][1] = __builtin_amdgcn_mfma_i32_16x16x64_i8(a1, b1, acc[1][1], 0, 0, 0);
    }
    short* Sb = g_S16 + (size_t)t * BHNN + (size_t)bh * Nn * Nn;
#pragma unroll
    for (int i = 0; i < 2; ++i)
#pragma unroll
        for (int j = 0; j < 2; ++j)
#pragma unroll
            for (int q = 0; q < 4; ++q) {
                int row = row0 + i * 16 + (lane >> 4) * 4 + q;
                int col = col0 + j * 16 + lr;
                Sb[row * Nn + col] = (short)acc[i][j][q];
            }
}

// ---------------- ALL-t aif IF + spiking softmax + sif IF (reg state) -------
__global__ __launch_bounds__(256) void attn_pipeline_all() {
    int rowid = blockIdx.x;                  // bh*512 + n
    size_t base = (size_t)rowid * Nn;
    int tid = threadIdx.x;
    __shared__ int   redI[4];
    __shared__ float redF[4];

    int   aq8[2]  = {4, 4};
    int   aac[2]  = {0, 0};
    float sq[2]   = {0.5f, 0.5f};
    int   sa[2]   = {0, 0};
    float yold[2] = {0.0f, 0.0f};

    for (int t = 0; t < Tn; ++t) {
        float st = (t + 1) < 6 ? (float)(t + 1) / 6.0f : 1.0f;
        const short* S = g_S16 + (size_t)t * BHNN;

        int X[2];
        int myMax = -128;
#pragma unroll
        for (int u = 0; u < 2; ++u) {
            int c = tid + u * 256;
            int s  = S[base + c];
            int q8 = aq8[u] + s;
            int a  = aac[u];
            bool pos = (q8 >= 8) && (a < 7);
            bool neg = (q8 < 0) && (a > -8);
            int o = pos ? 1 : (neg ? -1 : 0);
            aq8[u] = q8 - (o << 3);
            a += o;
            aac[u] = a;
            X[u] = a;
            myMax = max(myMax, a);
        }
        for (int off = 32; off; off >>= 1) myMax = max(myMax, __shfl_xor(myMax, off));
        if ((tid & 63) == 0) redI[tid >> 6] = myMax;
        __syncthreads();
        int M = max(max(redI[0], redI[1]), max(redI[2], redI[3]));

        float e[2];
        float mySum = 0.0f;
#pragma unroll
        for (int u = 0; u < 2; ++u) { e[u] = expf((float)(X[u] - M)); mySum += e[u]; }
        for (int off = 32; off; off >>= 1) mySum += __shfl_xor(mySum, off);
        if ((tid & 63) == 0) redF[tid >> 6] = mySum;
        __syncthreads();
        float Ssum = (redF[0] + redF[1]) + (redF[2] + redF[3]);

#pragma unroll
        for (int u = 0; u < 2; ++u) {
            int c = tid + u * 256;
            float y = (e[u] / Ssum) * st;
            float dlt = y - yold[u];
            yold[u] = y;
            float q = sq[u] + dlt;
            int a = sa[u];
            bool pos = ((q - 1.0f) >= 0.0f) && (a < 7);
            bool neg = (q < 0.0f) && (a > 0);
            float o = pos ? 1.0f : (neg ? -1.0f : 0.0f);
            sq[u] = q - o;
            a += (int)o;
            sa[u] = a;
            g_sifa8[(size_t)t * BHNN + base + c] = (int8_t)a;
            g_spk8[(size_t)t * BHNN + base + c]  = (int8_t)o;
        }
    }
}

// ------- PV (i8 MFMA, t-loop) + FUSED oif epilogue (reg state across t) -----
__global__ __launch_bounds__(256) void gemm_pv_oif_all() {
    int bh = blockIdx.y;
    int tm = blockIdx.x;
    int wave = threadIdx.x >> 6, lane = threadIdx.x & 63;
    int wr = wave >> 1, wc = wave & 1;
    int row0 = tm * 64 + wr * 32, col0 = wc * 32;
    int lr = lane & 15, kg = (lane >> 4) * 16;
    int b = bh / 12, h = bh - b * 12;

    float oq[2][2][4];
    int   oa[2][2][4];
#pragma unroll
    for (int i = 0; i < 2; ++i)
#pragma unroll
        for (int j = 0; j < 2; ++j)
#pragma unroll
            for (int q = 0; q < 4; ++q) { oq[i][j][q] = 0.5f; oa[i][j][q] = 0; }

    for (int t = 0; t < Tn; ++t) {
        const int8_t* Aa  = g_sifa8 + (size_t)t * BHNN + (size_t)bh * Nn * Nn;
        const int8_t* Asp = g_spk8  + (size_t)t * BHNN + (size_t)bh * Nn * Nn;
        const int8_t* Bb  = g_vT + ((size_t)t * BHn + bh) * Dn * 1024;
        i32x4 acc[2][2] = {};
        for (int kk = 0; kk < 512; kk += 64) {
            i32x4 a0 = *(const i32x4*)(Aa + (size_t)(row0 + lr) * 512 + kk + kg);
            i32x4 a1 = *(const i32x4*)(Aa + (size_t)(row0 + 16 + lr) * 512 + kk + kg);
            i32x4 b0 = *(const i32x4*)(Bb + (size_t)(col0 + lr) * 1024 + kk + kg);
            i32x4 b1 = *(const i32x4*)(Bb + (size_t)(col0 + 16 + lr) * 1024 + kk + kg);
            acc[0][0] = __builtin_amdgcn_mfma_i32_16x16x64_i8(a0, b0, acc[0][0], 0, 0, 0);
            acc[0][1] = __builtin_amdgcn_mfma_i32_16x16x64_i8(a0, b1, acc[0][1], 0, 0, 0);
            acc[1][0] = __builtin_amdgcn_mfma_i32_16x16x64_i8(a1, b0, acc[1][0], 0, 0, 0);
            acc[1][1] = __builtin_amdgcn_mfma_i32_16x16x64_i8(a1, b1, acc[1][1], 0, 0, 0);
        }
        for (int kk = 0; kk < 512; kk += 64) {
            i32x4 a0 = *(const i32x4*)(Asp + (size_t)(row0 + lr) * 512 + kk + kg);
            i32x4 a1 = *(const i32x4*)(Asp + (size_t)(row0 + 16 + lr) * 512 + kk + kg);
            i32x4 b0 = *(const i32x4*)(Bb + (size_t)(col0 + lr) * 1024 + 512 + kk + kg);
            i32x4 b1 = *(const i32x4*)(Bb + (size_t)(col0 + 16 + lr) * 1024 + 512 + kk + kg);
            acc[0][0] = __builtin_amdgcn_mfma_i32_16x16x64_i8(a0, b0, acc[0][0], 0, 0, 0);
            acc[0][1] = __builtin_amdgcn_mfma_i32_16x16x64_i8(a0, b1, acc[0][1], 0, 0, 0);
            acc[1][0] = __builtin_amdgcn_mfma_i32_16x16x64_i8(a1, b0, acc[1][0], 0, 0, 0);
            acc[1][1] = __builtin_amdgcn_mfma_i32_16x16x64_i8(a1, b1, acc[1][1], 0, 0, 0);
        }
        // fused oif epilogue (exact int -> f32, IF state in registers)
#pragma unroll
        for (int i = 0; i < 2; ++i)
#pragma unroll
            for (int j = 0; j < 2; ++j)
#pragma unroll
                for (int q = 0; q < 4; ++q) {
                    int row = row0 + i * 16 + (lane >> 4) * 4 + q;   // n
                    int col = col0 + j * 16 + lr;                    // d
                    float x = (float)acc[i][j][q];
                    float o = if_sym(x, oq[i][j][q], oa[i][j][q]);
                    size_t bn = (size_t)(b * Nn + row);
                    g_osp8i[(bn * 8 + t) * Cn + h * 64 + col] = (int8_t)o;
                }
    }
}

// ---------------- proj GEMM (frozen fp32 chain, int8-A) + FUSED pif ---------
__global__ __launch_bounds__(256, 8) void gemm_proj_pif_all(
    const float* __restrict__ B, float* __restrict__ outp)
{
    __shared__ __align__(16) float As[16][132];
    __shared__ __align__(16) float Bs[16][100];
    const int tid = threadIdx.x;
    const int m0 = blockIdx.y * 128;
    const int j0 = blockIdx.x * 96;
    const int ty = tid >> 4, tx = tid & 15;

    float acc[8][6];
#pragma unroll
    for (int i = 0; i < 8; ++i)
#pragma unroll
        for (int j = 0; j < 6; ++j) acc[i][j] = 0.0f;

    for (int k0 = 0; k0 < Cn; k0 += 16) {
        {   // A staging: int8 spikes -> exact fp32
            int row = tid >> 1;
            int c8 = (tid & 1) * 8;
            s8x8 v = *(const s8x8*)(g_osp8i + (size_t)(m0 + row) * Cn + k0 + c8);
#pragma unroll
            for (int j = 0; j < 8; ++j) As[c8 + j][row] = (float)v[j];
        }
#pragma unroll
        for (int u = 0; u < 3; ++u) {
            int f = tid + u * 256;
            int r2 = f >> 3;
            int c2 = (f & 7) * 2;
            float2 bv = *(const float2*)(B + (size_t)(j0 + r2) * Cn + k0 + c2);
            Bs[c2][r2] = bv.x; Bs[c2 + 1][r2] = bv.y;
        }
        __syncthreads();
#pragma unroll
        for (int k = 0; k < 16; ++k) {
            alignas(16) float a[8];
            alignas(8)  float b[6];
            *(float4*)(a)     = *(const float4*)&As[k][ty * 8];
            *(float4*)(a + 4) = *(const float4*)&As[k][ty * 8 + 4];
#pragma unroll
            for (int u = 0; u < 3; ++u) {
                float2 t = *(const float2*)&Bs[k][tx * 2 + 32 * u];
                b[2 * u] = t.x; b[2 * u + 1] = t.y;
            }
#pragma unroll
            for (int i = 0; i < 8; ++i)
#pragma unroll
                for (int j = 0; j < 6; ++j)
                    acc[i][j] = fmaf(a[i], b[j], acc[i][j]);
        }
        __syncthreads();
    }

    // fused pif epilogue
    const size_t bn = (size_t)((m0 + ty * 8) >> 3);
#pragma unroll
    for (int u = 0; u < 3; ++u) {
        size_t cbase = bn * Cn + j0 + 32 * u + tx * 2;
        float q0 = 0.5f, q1 = 0.5f;
        int   a0 = 0,    a1 = 0;
#pragma unroll
        for (int t = 0; t < Tn; ++t) {
            float o0 = if_sym(acc[t][2 * u],     q0, a0);
            float o1 = if_sym(acc[t][2 * u + 1], q1, a1);
            float2 st; st.x = o0; st.y = o1;
            *(float2*)(outp + (size_t)t * BNC + cbase) = st;
        }
    }
}

extern "C" void kernel_launch(void* const* d_in, const int* in_sizes, int n_in,
                              void* d_out, int out_size, void* d_ws, size_t ws_size,
                              hipStream_t stream) {
    (void)in_sizes; (void)n_in; (void)out_size; (void)d_ws; (void)ws_size;
    const float* x      = (const float*)d_in[0];
    const float* w_qkv  = (const float*)d_in[1];
    const float* w_proj = (const float*)d_in[2];
    float* outp = (float*)d_out;

    // qkv GEMM [32768 x 2304] K=768 with fused q/k/v IF epilogue
    gemm_qkv_fused<<<dim3(C3n / 96, (Tn * BNn) / 128), 256, 0, stream>>>(x, w_qkv);
    // transposed V operand
    vT_build<<<Tn * BHn, 256, 0, stream>>>();
    // all-t attn logits (i8 MFMA, exact)
    gemm_attn_all<<<dim3(64, BHn, Tn), 256, 0, stream>>>();
    // all-t aif + softmax + sif recurrence (reg state)
    attn_pipeline_all<<<BHn * Nn, 256, 0, stream>>>();
    // all-t PV (i8 MFMA) + fused oif
    gemm_pv_oif_all<<<dim3(8, BHn), 256, 0, stream>>>();
    // proj GEMM [32768 x 768] K=768 with fused pif epilogue -> output
    gemm_proj_pif_all<<<dim3(Cn / 96, (Tn * BNn) / 128), 256, 0, stream>>>(w_proj, outp);
}

// Round 17
// 2691.711 us; speedup vs baseline: 5.9803x; 5.9803x over previous
//
#include <hip/hip_runtime.h>
#include <stdint.h>

typedef __attribute__((ext_vector_type(4))) float f32x4;
typedef __attribute__((ext_vector_type(4))) int   i32x4;
typedef __attribute__((ext_vector_type(8))) char  s8x8;
typedef __attribute__((ext_vector_type(16))) char s8x16;
typedef unsigned short u16;

constexpr int    Tn  = 8;
constexpr int    Nn  = 512;
constexpr int    Cn  = 768;
constexpr int    Dn  = 64;
constexpr int    BHn = 96;
constexpr int    BNn = 4096;
constexpr int    C3n = 2304;
constexpr size_t BHND = 3145728;     // B*H*N*D
constexpr size_t BHNN = 25165824;    // B*H*N*N
constexpr size_t BNC  = 3145728;     // B*N*C

// ---- all buffers produced-before-consumed each call (no persistent state) ----
__device__ __attribute__((aligned(16))) int8_t g_A1[(size_t)Tn * BHND * 2];  // [t][bh][n][128]
__device__ __attribute__((aligned(16))) int8_t g_B1[(size_t)Tn * BHND * 2];
__device__ __attribute__((aligned(16))) short  g_S16[(size_t)Tn * BHNN];     // [t][bh][n][n]
__device__ __attribute__((aligned(16))) int8_t g_v8 [(size_t)Tn * BHND];     // [t][bh][n][d]
__device__ __attribute__((aligned(16))) int8_t g_vd8[(size_t)Tn * BHND];     // [t][bh][n][d]
__device__ __attribute__((aligned(16))) int8_t g_vT[(size_t)Tn * BHn * Dn * 1024]; // [t][bh][d][1024]
__device__ __attribute__((aligned(16))) int8_t g_sifa8[(size_t)Tn * BHNN];   // sif acc after step t
__device__ __attribute__((aligned(16))) int8_t g_spk8[(size_t)Tn * BHNN];    // sif spike at step t
__device__ __attribute__((aligned(16))) int8_t g_osp8i[(size_t)BNn * Tn * Cn]; // [bn*8+t][C]

static __device__ __forceinline__ void st2i8(int8_t* p, int v0, int v1) {
    *(short*)p = (short)((v0 & 0xff) | (v1 << 8));
}

// symmetric IF neuron step (pos_max=7, neg_min=-8)
static __device__ __forceinline__ float if_sym(float x, float& q, int& a) {
    float q2 = q + x;
    bool pos = ((q2 - 1.0f) >= 0.0f) && (a < 7);
    bool neg = (q2 < 0.0f) && (a > -8);
    float out = pos ? 1.0f : (neg ? -1.0f : 0.0f);
    q = q2 - out;
    a += (int)out;
    return out;
}

// ---------------- qkv GEMM (frozen fp32 chain) + FUSED q/k/v IF epilogue ----
// NOTE: no __launch_bounds__ second arg — r16 showed the compiler honors a
// residency request by capping VGPR (56->32), spilling acc[8][6] to scratch
// (FETCH 484MB->14.7GB, 9x slower). 43% occupancy + 79% VALUBusy is the
// constrained optimum for this structure.
__global__ __launch_bounds__(256) void gemm_qkv_fused(
    const float* __restrict__ X, const float* __restrict__ B)
{
    __shared__ __align__(16) float As[16][132];   // 128+4
    __shared__ __align__(16) float Bs[16][100];   // 96+4
    const int tid = threadIdx.x;
    const int m0 = blockIdx.y * 128;
    const int j0 = blockIdx.x * 96;
    const int ty = tid >> 4, tx = tid & 15;

    float acc[8][6];
#pragma unroll
    for (int i = 0; i < 8; ++i)
#pragma unroll
        for (int j = 0; j < 6; ++j) acc[i][j] = 0.0f;

    for (int k0 = 0; k0 < Cn; k0 += 16) {
#pragma unroll
        for (int u = 0; u < 2; ++u) {
            int f = tid + u * 256;
            int row = f >> 2;
            int c4 = (f & 3) * 4;
            int m = m0 + row;
            int t = m & 7, bn = m >> 3;
            int b = bn >> 9, n = bn & 511;
            const float* xr = X + ((size_t)((t * 8 + b) * Nn + n)) * Cn;
            float4 av = *(const float4*)(xr + k0 + c4);
            As[c4 + 0][row] = av.x; As[c4 + 1][row] = av.y;
            As[c4 + 2][row] = av.z; As[c4 + 3][row] = av.w;
        }
#pragma unroll
        for (int u = 0; u < 3; ++u) {
            int f = tid + u * 256;
            int row = f >> 3;
            int c2 = (f & 7) * 2;
            float2 bv = *(const float2*)(B + (size_t)(j0 + row) * Cn + k0 + c2);
            Bs[c2][row] = bv.x; Bs[c2 + 1][row] = bv.y;
        }
        __syncthreads();
#pragma unroll
        for (int k = 0; k < 16; ++k) {
            alignas(16) float a[8];
            alignas(8)  float b[6];
            *(float4*)(a)     = *(const float4*)&As[k][ty * 8];
            *(float4*)(a + 4) = *(const float4*)&As[k][ty * 8 + 4];
#pragma unroll
            for (int u = 0; u < 3; ++u) {
                float2 t = *(const float2*)&Bs[k][tx * 2 + 32 * u];
                b[2 * u] = t.x; b[2 * u + 1] = t.y;
            }
#pragma unroll
            for (int i = 0; i < 8; ++i)
#pragma unroll
                for (int j = 0; j < 6; ++j)
                    acc[i][j] = fmaf(a[i], b[j], acc[i][j]);
        }
        __syncthreads();
    }

    // fused IF epilogue: 6 independent 8-step chains per thread
    const int type = (j0 >= 1536) ? 2 : ((j0 >= 768) ? 1 : 0);
    const int bn = (m0 + ty * 8) >> 3;
    const int b = bn >> 9, n = bn & 511;
#pragma unroll
    for (int u = 0; u < 3; ++u) {
        int c  = j0 + 32 * u + tx * 2;
        int cl = c - type * 768;
        int h = cl >> 6, d = cl & 63;
        int bh = b * 12 + h;
        float q0 = 0.5f, q1 = 0.5f;
        int   a0 = 0,    a1 = 0;
#pragma unroll
        for (int t = 0; t < Tn; ++t) {
            float o0 = if_sym(acc[t][2 * u],     q0, a0);
            float o1 = if_sym(acc[t][2 * u + 1], q1, a1);
            if (type == 0) {
                size_t p = (((size_t)t * BHn + bh) * Nn + n) * 128 + d;
                st2i8(&g_A1[p],      a0,      a1);
                st2i8(&g_A1[p + 64], (int)o0, (int)o1);
            } else if (type == 1) {
                size_t p = (((size_t)t * BHn + bh) * Nn + n) * 128 + d;
                st2i8(&g_B1[p],      (int)o0,      (int)o1);
                st2i8(&g_B1[p + 64], a0 - (int)o0, a1 - (int)o1);
            } else {
                size_t p = (size_t)t * BHND + ((size_t)bh * Nn + n) * 64 + d;
                st2i8(&g_v8[p],  (int)o0,      (int)o1);
                st2i8(&g_vd8[p], a0 - (int)o0, a1 - (int)o1);
            }
        }
    }
}

// ---------------- build vT[t][bh][d][1024] (LDS-tiled transpose) ------------
__global__ __launch_bounds__(256) void vT_build() {
    int bh = blockIdx.x % BHn;
    int t  = blockIdx.x / BHn;
    const int8_t* src0 = g_v8  + (size_t)t * BHND + (size_t)bh * Nn * Dn;
    const int8_t* src1 = g_vd8 + (size_t)t * BHND + (size_t)bh * Nn * Dn;
    int8_t* dst = g_vT + ((size_t)t * BHn + bh) * Dn * 1024;
    __shared__ __align__(16) int8_t tile[64][80];
    int tid = threadIdx.x;

    for (int s = 0; s < 2; ++s) {
        const int8_t* src = s ? src1 : src0;
        int koff = s * 512;
        for (int nb = 0; nb < Nn; nb += 64) {
            {
                int n  = tid >> 2;
                int d0 = (tid & 3) * 16;
                s8x16 v = *(const s8x16*)(src + (size_t)(nb + n) * Dn + d0);
                *(s8x16*)&tile[n][d0] = v;
            }
            __syncthreads();
            {
                int d  = tid >> 2;
                int n0 = (tid & 3) * 16;
                s8x16 o;
#pragma unroll
                for (int j = 0; j < 16; ++j) o[j] = tile[n0 + j][d];
                *(s8x16*)(dst + (size_t)d * 1024 + koff + nb + n0) = o;
            }
            __syncthreads();
        }
    }
}

// ---------------- attn logits for ALL t (i8 MFMA, exact int32) --------------
__global__ __launch_bounds__(256) void gemm_attn_all() {
    int t = blockIdx.z;
    int bh = blockIdx.y;
    int tm = blockIdx.x >> 3, tn = blockIdx.x & 7;
    int wave = threadIdx.x >> 6, lane = threadIdx.x & 63;
    int wr = wave >> 1, wc = wave & 1;
    int row0 = tm * 64 + wr * 32, col0 = tn * 64 + wc * 32;
    const int8_t* Ab = g_A1 + ((size_t)t * BHn + bh) * Nn * 128;
    const int8_t* Bb = g_B1 + ((size_t)t * BHn + bh) * Nn * 128;
    int lr = lane & 15, kg = (lane >> 4) * 16;
    i32x4 acc[2][2] = {};
#pragma unroll
    for (int kk = 0; kk < 128; kk += 64) {
        i32x4 a0 = *(const i32x4*)(Ab + (size_t)(row0 + lr) * 128 + kk + kg);
        i32x4 a1 = *(const i32x4*)(Ab + (size_t)(row0 + 16 + lr) * 128 + kk + kg);
        i32x4 b0 = *(const i32x4*)(Bb + (size_t)(col0 + lr) * 128 + kk + kg);
        i32x4 b1 = *(const i32x4*)(Bb + (size_t)(col0 + 16 + lr) * 128 + kk + kg);
        acc[0][0] = __builtin_amdgcn_mfma_i32_16x16x64_i8(a0, b0, acc[0][0], 0, 0, 0);
        acc[0][1] = __builtin_amdgcn_mfma_i32_16x16x64_i8(a0, b1, acc[0][1], 0, 0, 0);
        acc[1][0] = __builtin_amdgcn_mfma_i32_16x16x64_i8(a1, b0, acc[1][0], 0, 0, 0);
        acc[1][1] = __builtin_amdgcn_mfma_i32_16x16x64_i8(a1, b1, acc[1][1], 0, 0, 0);
    }
    short* Sb = g_S16 + (size_t)t * BHNN + (size_t)bh * Nn * Nn;
#pragma unroll
    for (int i = 0; i < 2; ++i)
#pragma unroll
        for (int j = 0; j < 2; ++j)
#pragma unroll
            for (int q = 0; q < 4; ++q) {
                int row = row0 + i * 16 + (lane >> 4) * 4 + q;
                int col = col0 + j * 16 + lr;
                Sb[row * Nn + col] = (short)acc[i][j][q];
            }
}

// ---------------- ALL-t aif IF + spiking softmax + sif IF (reg state) -------
__global__ __launch_bounds__(256) void attn_pipeline_all() {
    int rowid = blockIdx.x;                  // bh*512 + n
    size_t base = (size_t)rowid * Nn;
    int tid = threadIdx.x;
    __shared__ int   redI[4];
    __shared__ float redF[4];

    int   aq8[2]  = {4, 4};
    int   aac[2]  = {0, 0};
    float sq[2]   = {0.5f, 0.5f};
    int   sa[2]   = {0, 0};
    float yold[2] = {0.0f, 0.0f};

    for (int t = 0; t < Tn; ++t) {
        float st = (t + 1) < 6 ? (float)(t + 1) / 6.0f : 1.0f;
        const short* S = g_S16 + (size_t)t * BHNN;

        int X[2];
        int myMax = -128;
#pragma unroll
        for (int u = 0; u < 2; ++u) {
            int c = tid + u * 256;
            int s  = S[base + c];
            int q8 = aq8[u] + s;
            int a  = aac[u];
            bool pos = (q8 >= 8) && (a < 7);
            bool neg = (q8 < 0) && (a > -8);
            int o = pos ? 1 : (neg ? -1 : 0);
            aq8[u] = q8 - (o << 3);
            a += o;
            aac[u] = a;
            X[u] = a;
            myMax = max(myMax, a);
        }
        for (int off = 32; off; off >>= 1) myMax = max(myMax, __shfl_xor(myMax, off));
        if ((tid & 63) == 0) redI[tid >> 6] = myMax;
        __syncthreads();
        int M = max(max(redI[0], redI[1]), max(redI[2], redI[3]));

        float e[2];
        float mySum = 0.0f;
#pragma unroll
        for (int u = 0; u < 2; ++u) { e[u] = expf((float)(X[u] - M)); mySum += e[u]; }
        for (int off = 32; off; off >>= 1) mySum += __shfl_xor(mySum, off);
        if ((tid & 63) == 0) redF[tid >> 6] = mySum;
        __syncthreads();
        float Ssum = (redF[0] + redF[1]) + (redF[2] + redF[3]);

#pragma unroll
        for (int u = 0; u < 2; ++u) {
            int c = tid + u * 256;
            float y = (e[u] / Ssum) * st;
            float dlt = y - yold[u];
            yold[u] = y;
            float q = sq[u] + dlt;
            int a = sa[u];
            bool pos = ((q - 1.0f) >= 0.0f) && (a < 7);
            bool neg = (q < 0.0f) && (a > 0);
            float o = pos ? 1.0f : (neg ? -1.0f : 0.0f);
            sq[u] = q - o;
            a += (int)o;
            sa[u] = a;
            g_sifa8[(size_t)t * BHNN + base + c] = (int8_t)a;
            g_spk8[(size_t)t * BHNN + base + c]  = (int8_t)o;
        }
    }
}

// ------- PV (i8 MFMA, t-loop) + FUSED oif epilogue (reg state across t) -----
__global__ __launch_bounds__(256) void gemm_pv_oif_all() {
    int bh = blockIdx.y;
    int tm = blockIdx.x;
    int wave = threadIdx.x >> 6, lane = threadIdx.x & 63;
    int wr = wave >> 1, wc = wave & 1;
    int row0 = tm * 64 + wr * 32, col0 = wc * 32;
    int lr = lane & 15, kg = (lane >> 4) * 16;
    int b = bh / 12, h = bh - b * 12;

    float oq[2][2][4];
    int   oa[2][2][4];
#pragma unroll
    for (int i = 0; i < 2; ++i)
#pragma unroll
        for (int j = 0; j < 2; ++j)
#pragma unroll
            for (int q = 0; q < 4; ++q) { oq[i][j][q] = 0.5f; oa[i][j][q] = 0; }

    for (int t = 0; t < Tn; ++t) {
        const int8_t* Aa  = g_sifa8 + (size_t)t * BHNN + (size_t)bh * Nn * Nn;
        const int8_t* Asp = g_spk8  + (size_t)t * BHNN + (size_t)bh * Nn * Nn;
        const int8_t* Bb  = g_vT + ((size_t)t * BHn + bh) * Dn * 1024;
        i32x4 acc[2][2] = {};
        for (int kk = 0; kk < 512; kk += 64) {
            i32x4 a0 = *(const i32x4*)(Aa + (size_t)(row0 + lr) * 512 + kk + kg);
            i32x4 a1 = *(const i32x4*)(Aa + (size_t)(row0 + 16 + lr) * 512 + kk + kg);
            i32x4 b0 = *(const i32x4*)(Bb + (size_t)(col0 + lr) * 1024 + kk + kg);
            i32x4 b1 = *(const i32x4*)(Bb + (size_t)(col0 + 16 + lr) * 1024 + kk + kg);
            acc[0][0] = __builtin_amdgcn_mfma_i32_16x16x64_i8(a0, b0, acc[0][0], 0, 0, 0);
            acc[0][1] = __builtin_amdgcn_mfma_i32_16x16x64_i8(a0, b1, acc[0][1], 0, 0, 0);
            acc[1][0] = __builtin_amdgcn_mfma_i32_16x16x64_i8(a1, b0, acc[1][0], 0, 0, 0);
            acc[1][1] = __builtin_amdgcn_mfma_i32_16x16x64_i8(a1, b1, acc[1][1], 0, 0, 0);
        }
        for (int kk = 0; kk < 512; kk += 64) {
            i32x4 a0 = *(const i32x4*)(Asp + (size_t)(row0 + lr) * 512 + kk + kg);
            i32x4 a1 = *(const i32x4*)(Asp + (size_t)(row0 + 16 + lr) * 512 + kk + kg);
            i32x4 b0 = *(const i32x4*)(Bb + (size_t)(col0 + lr) * 1024 + 512 + kk + kg);
            i32x4 b1 = *(const i32x4*)(Bb + (size_t)(col0 + 16 + lr) * 1024 + 512 + kk + kg);
            acc[0][0] = __builtin_amdgcn_mfma_i32_16x16x64_i8(a0, b0, acc[0][0], 0, 0, 0);
            acc[0][1] = __builtin_amdgcn_mfma_i32_16x16x64_i8(a0, b1, acc[0][1], 0, 0, 0);
            acc[1][0] = __builtin_amdgcn_mfma_i32_16x16x64_i8(a1, b0, acc[1][0], 0, 0, 0);
            acc[1][1] = __builtin_amdgcn_mfma_i32_16x16x64_i8(a1, b1, acc[1][1], 0, 0, 0);
        }
        // fused oif epilogue (exact int -> f32, IF state in registers)
#pragma unroll
        for (int i = 0; i < 2; ++i)
#pragma unroll
            for (int j = 0; j < 2; ++j)
#pragma unroll
                for (int q = 0; q < 4; ++q) {
                    int row = row0 + i * 16 + (lane >> 4) * 4 + q;   // n
                    int col = col0 + j * 16 + lr;                    // d
                    float x = (float)acc[i][j][q];
                    float o = if_sym(x, oq[i][j][q], oa[i][j][q]);
                    size_t bn = (size_t)(b * Nn + row);
                    g_osp8i[(bn * 8 + t) * Cn + h * 64 + col] = (int8_t)o;
                }
    }
}

// ---------------- proj GEMM (frozen fp32 chain, int8-A) + FUSED pif ---------
__global__ __launch_bounds__(256) void gemm_proj_pif_all(
    const float* __restrict__ B, float* __restrict__ outp)
{
    __shared__ __align__(16) float As[16][132];
    __shared__ __align__(16) float Bs[16][100];
    const int tid = threadIdx.x;
    const int m0 = blockIdx.y * 128;
    const int j0 = blockIdx.x * 96;
    const int ty = tid >> 4, tx = tid & 15;

    float acc[8][6];
#pragma unroll
    for (int i = 0; i < 8; ++i)
#pragma unroll
        for (int j = 0; j < 6; ++j) acc[i][j] = 0.0f;

    for (int k0 = 0; k0 < Cn; k0 += 16) {
        {   // A staging: int8 spikes -> exact fp32
            int row = tid >> 1;
            int c8 = (tid & 1) * 8;
            s8x8 v = *(const s8x8*)(g_osp8i + (size_t)(m0 + row) * Cn + k0 + c8);
#pragma unroll
            for (int j = 0; j < 8; ++j) As[c8 + j][row] = (float)v[j];
        }
#pragma unroll
        for (int u = 0; u < 3; ++u) {
            int f = tid + u * 256;
            int r2 = f >> 3;
            int c2 = (f & 7) * 2;
            float2 bv = *(const float2*)(B + (size_t)(j0 + r2) * Cn + k0 + c2);
            Bs[c2][r2] = bv.x; Bs[c2 + 1][r2] = bv.y;
        }
        __syncthreads();
#pragma unroll
        for (int k = 0; k < 16; ++k) {
            alignas(16) float a[8];
            alignas(8)  float b[6];
            *(float4*)(a)     = *(const float4*)&As[k][ty * 8];
            *(float4*)(a + 4) = *(const float4*)&As[k][ty * 8 + 4];
#pragma unroll
            for (int u = 0; u < 3; ++u) {
                float2 t = *(const float2*)&Bs[k][tx * 2 + 32 * u];
                b[2 * u] = t.x; b[2 * u + 1] = t.y;
            }
#pragma unroll
            for (int i = 0; i < 8; ++i)
#pragma unroll
                for (int j = 0; j < 6; ++j)
                    acc[i][j] = fmaf(a[i], b[j], acc[i][j]);
        }
        __syncthreads();
    }

    // fused pif epilogue
    const size_t bn = (size_t)((m0 + ty * 8) >> 3);
#pragma unroll
    for (int u = 0; u < 3; ++u) {
        size_t cbase = bn * Cn + j0 + 32 * u + tx * 2;
        float q0 = 0.5f, q1 = 0.5f;
        int   a0 = 0,    a1 = 0;
#pragma unroll
        for (int t = 0; t < Tn; ++t) {
            float o0 = if_sym(acc[t][2 * u],     q0, a0);
            float o1 = if_sym(acc[t][2 * u + 1], q1, a1);
            float2 st; st.x = o0; st.y = o1;
            *(float2*)(outp + (size_t)t * BNC + cbase) = st;
        }
    }
}

extern "C" void kernel_launch(void* const* d_in, const int* in_sizes, int n_in,
                              void* d_out, int out_size, void* d_ws, size_t ws_size,
                              hipStream_t stream) {
    (void)in_sizes; (void)n_in; (void)out_size; (void)d_ws; (void)ws_size;
    const float* x      = (const float*)d_in[0];
    const float* w_qkv  = (const float*)d_in[1];
    const float* w_proj = (const float*)d_in[2];
    float* outp = (float*)d_out;

    // qkv GEMM [32768 x 2304] K=768 with fused q/k/v IF epilogue
    gemm_qkv_fused<<<dim3(C3n / 96, (Tn * BNn) / 128), 256, 0, stream>>>(x, w_qkv);
    // transposed V operand
    vT_build<<<Tn * BHn, 256, 0, stream>>>();
    // all-t attn logits (i8 MFMA, exact)
    gemm_attn_all<<<dim3(64, BHn, Tn), 256, 0, stream>>>();
    // all-t aif + softmax + sif recurrence (reg state)
    attn_pipeline_all<<<BHn * Nn, 256, 0, stream>>>();
    // all-t PV (i8 MFMA) + fused oif
    gemm_pv_oif_all<<<dim3(8, BHn), 256, 0, stream>>>();
    // proj GEMM [32768 x 768] K=768 with fused pif epilogue -> output
    gemm_proj_pif_all<<<dim3(Cn / 96, (Tn * BNn) / 128), 256, 0, stream>>>(w_proj, outp);
}

// Round 18
// 2669.111 us; speedup vs baseline: 6.0309x; 1.0085x over previous
//
#include <hip/hip_runtime.h>
#include <stdint.h>

typedef __attribute__((ext_vector_type(4))) float f32x4;
typedef __attribute__((ext_vector_type(4))) int   i32x4;
typedef __attribute__((ext_vector_type(8))) char  s8x8;
typedef __attribute__((ext_vector_type(16))) char s8x16;
typedef unsigned short u16;

constexpr int    Tn  = 8;
constexpr int    Nn  = 512;
constexpr int    Cn  = 768;
constexpr int    Dn  = 64;
constexpr int    BHn = 96;
constexpr int    BNn = 4096;
constexpr int    C3n = 2304;
constexpr size_t BHND = 3145728;     // B*H*N*D
constexpr size_t BHNN = 25165824;    // B*H*N*N
constexpr size_t BNC  = 3145728;     // B*N*C

// ---- all buffers produced-before-consumed each call (no persistent state) ----
__device__ __attribute__((aligned(16))) int8_t g_A1[(size_t)Tn * BHND * 2];  // [t][bh][n][128]
__device__ __attribute__((aligned(16))) int8_t g_B1[(size_t)Tn * BHND * 2];
__device__ __attribute__((aligned(16))) short  g_S16[(size_t)Tn * BHNN];     // [t][bh][n][n]
__device__ __attribute__((aligned(16))) int8_t g_v8 [(size_t)Tn * BHND];     // [t][bh][n][d]
__device__ __attribute__((aligned(16))) int8_t g_vd8[(size_t)Tn * BHND];     // [t][bh][n][d]
__device__ __attribute__((aligned(16))) int8_t g_vT[(size_t)Tn * BHn * Dn * 1024]; // [t][bh][d][1024]
__device__ __attribute__((aligned(16))) int8_t g_sifa8[(size_t)Tn * BHNN];   // sif acc after step t
__device__ __attribute__((aligned(16))) int8_t g_spk8[(size_t)Tn * BHNN];    // sif spike at step t
__device__ __attribute__((aligned(16))) int8_t g_osp8i[(size_t)BNn * Tn * Cn]; // [bn*8+t][C]

// symmetric IF neuron step (pos_max=7, neg_min=-8)
static __device__ __forceinline__ float if_sym(float x, float& q, int& a) {
    float q2 = q + x;
    bool pos = ((q2 - 1.0f) >= 0.0f) && (a < 7);
    bool neg = (q2 < 0.0f) && (a > -8);
    float out = pos ? 1.0f : (neg ? -1.0f : 0.0f);
    q = q2 - out;
    a += (int)out;
    return out;
}

// ---------------- qkv GEMM 128x128 (frozen fp32 chain) + FUSED q/k/v IF -----
// LDS-BW model: 84TF ceiling of 128x96 tile was LDS bytes/FMA-bound (1.17
// B/FMA). 128x128, 8x8/thread: 1.0 B/FMA, 8-consecutive-col epilogue -> 8B
// int8 stores. Per-output k-ascending fmaf chain unchanged -> bit-exact.
__global__ __launch_bounds__(256) void gemm_qkv_fused(
    const float* __restrict__ X, const float* __restrict__ B)
{
    __shared__ __align__(16) float As[16][132];   // 128+4
    __shared__ __align__(16) float Bs[16][132];
    const int tid = threadIdx.x;
    const int m0 = blockIdx.y * 128;
    const int j0 = blockIdx.x * 128;
    const int ty = tid >> 4, tx = tid & 15;

    float acc[8][8];
#pragma unroll
    for (int i = 0; i < 8; ++i)
#pragma unroll
        for (int j = 0; j < 8; ++j) acc[i][j] = 0.0f;

    for (int k0 = 0; k0 < Cn; k0 += 16) {
#pragma unroll
        for (int u = 0; u < 2; ++u) {
            int f = tid + u * 256;
            int row = f >> 2;
            int c4 = (f & 3) * 4;
            int m = m0 + row;
            int t = m & 7, bn = m >> 3;
            int b = bn >> 9, n = bn & 511;
            const float* xr = X + ((size_t)((t * 8 + b) * Nn + n)) * Cn;
            float4 av = *(const float4*)(xr + k0 + c4);
            As[c4 + 0][row] = av.x; As[c4 + 1][row] = av.y;
            As[c4 + 2][row] = av.z; As[c4 + 3][row] = av.w;
        }
#pragma unroll
        for (int u = 0; u < 2; ++u) {
            int f = tid + u * 256;
            int row = f >> 2;
            int c4 = (f & 3) * 4;
            float4 bv = *(const float4*)(B + (size_t)(j0 + row) * Cn + k0 + c4);
            Bs[c4 + 0][row] = bv.x; Bs[c4 + 1][row] = bv.y;
            Bs[c4 + 2][row] = bv.z; Bs[c4 + 3][row] = bv.w;
        }
        __syncthreads();
#pragma unroll
        for (int k = 0; k < 16; ++k) {
            alignas(16) float a[8];
            alignas(16) float b[8];
            *(float4*)(a)     = *(const float4*)&As[k][ty * 8];
            *(float4*)(a + 4) = *(const float4*)&As[k][ty * 8 + 4];
            *(float4*)(b)     = *(const float4*)&Bs[k][tx * 8];
            *(float4*)(b + 4) = *(const float4*)&Bs[k][tx * 8 + 4];
#pragma unroll
            for (int i = 0; i < 8; ++i)
#pragma unroll
                for (int j = 0; j < 8; ++j)
                    acc[i][j] = fmaf(a[i], b[j], acc[i][j]);
        }
        __syncthreads();
    }

    // fused IF epilogue: 8 consecutive cols per thread, 8 chains over t=i.
    const int col0 = j0 + tx * 8;
    const int type = (col0 >= 1536) ? 2 : ((col0 >= 768) ? 1 : 0);
    const int cl = col0 - type * 768;
    const int h = cl >> 6, d0 = cl & 63;     // 8 cols within one head
    const int bn = (m0 + ty * 8) >> 3;
    const int b = bn >> 9, n = bn & 511;
    const int bh = b * 12 + h;

    float q[8]; int a[8];
#pragma unroll
    for (int j = 0; j < 8; ++j) { q[j] = 0.5f; a[j] = 0; }
#pragma unroll
    for (int t = 0; t < Tn; ++t) {
        s8x8 w0, w1;
#pragma unroll
        for (int j = 0; j < 8; ++j) {
            float o = if_sym(acc[t][j], q[j], a[j]);
            if (type == 0)      { w0[j] = (int8_t)a[j];            w1[j] = (int8_t)o; }
            else if (type == 1) { w0[j] = (int8_t)o;               w1[j] = (int8_t)(a[j] - (int)o); }
            else                { w0[j] = (int8_t)o;               w1[j] = (int8_t)(a[j] - (int)o); }
        }
        if (type == 0) {
            size_t p = (((size_t)t * BHn + bh) * Nn + n) * 128 + d0;
            *(s8x8*)&g_A1[p]      = w0;          // acc_q half
            *(s8x8*)&g_A1[p + 64] = w1;          // q spike half
        } else if (type == 1) {
            size_t p = (((size_t)t * BHn + bh) * Nn + n) * 128 + d0;
            *(s8x8*)&g_B1[p]      = w0;          // k spike
            *(s8x8*)&g_B1[p + 64] = w1;          // k_acc - k
        } else {
            size_t p = (size_t)t * BHND + ((size_t)bh * Nn + n) * 64 + d0;
            *(s8x8*)&g_v8[p]  = w0;              // v spike
            *(s8x8*)&g_vd8[p] = w1;              // v_acc - v
        }
    }
}

// ---------------- build vT[t][bh][d][1024] (LDS-tiled transpose) ------------
__global__ __launch_bounds__(256) void vT_build() {
    int bh = blockIdx.x % BHn;
    int t  = blockIdx.x / BHn;
    const int8_t* src0 = g_v8  + (size_t)t * BHND + (size_t)bh * Nn * Dn;
    const int8_t* src1 = g_vd8 + (size_t)t * BHND + (size_t)bh * Nn * Dn;
    int8_t* dst = g_vT + ((size_t)t * BHn + bh) * Dn * 1024;
    __shared__ __align__(16) int8_t tile[64][80];
    int tid = threadIdx.x;

    for (int s = 0; s < 2; ++s) {
        const int8_t* src = s ? src1 : src0;
        int koff = s * 512;
        for (int nb = 0; nb < Nn; nb += 64) {
            {
                int n  = tid >> 2;
                int d0 = (tid & 3) * 16;
                s8x16 v = *(const s8x16*)(src + (size_t)(nb + n) * Dn + d0);
                *(s8x16*)&tile[n][d0] = v;
            }
            __syncthreads();
            {
                int d  = tid >> 2;
                int n0 = (tid & 3) * 16;
                s8x16 o;
#pragma unroll
                for (int j = 0; j < 16; ++j) o[j] = tile[n0 + j][d];
                *(s8x16*)(dst + (size_t)d * 1024 + koff + nb + n0) = o;
            }
            __syncthreads();
        }
    }
}

// ---------------- attn logits for ALL t (i8 MFMA, exact int32) --------------
__global__ __launch_bounds__(256) void gemm_attn_all() {
    int t = blockIdx.z;
    int bh = blockIdx.y;
    int tm = blockIdx.x >> 3, tn = blockIdx.x & 7;
    int wave = threadIdx.x >> 6, lane = threadIdx.x & 63;
    int wr = wave >> 1, wc = wave & 1;
    int row0 = tm * 64 + wr * 32, col0 = tn * 64 + wc * 32;
    const int8_t* Ab = g_A1 + ((size_t)t * BHn + bh) * Nn * 128;
    const int8_t* Bb = g_B1 + ((size_t)t * BHn + bh) * Nn * 128;
    int lr = lane & 15, kg = (lane >> 4) * 16;
    i32x4 acc[2][2] = {};
#pragma unroll
    for (int kk = 0; kk < 128; kk += 64) {
        i32x4 a0 = *(const i32x4*)(Ab + (size_t)(row0 + lr) * 128 + kk + kg);
        i32x4 a1 = *(const i32x4*)(Ab + (size_t)(row0 + 16 + lr) * 128 + kk + kg);
        i32x4 b0 = *(const i32x4*)(Bb + (size_t)(col0 + lr) * 128 + kk + kg);
        i32x4 b1 = *(const i32x4*)(Bb + (size_t)(col0 + 16 + lr) * 128 + kk + kg);
        acc[0][0] = __builtin_amdgcn_mfma_i32_16x16x64_i8(a0, b0, acc[0][0], 0, 0, 0);
        acc[0][1] = __builtin_amdgcn_mfma_i32_16x16x64_i8(a0, b1, acc[0][1], 0, 0, 0);
        acc[1][0] = __builtin_amdgcn_mfma_i32_16x16x64_i8(a1, b0, acc[1][0], 0, 0, 0);
        acc[1][1] = __builtin_amdgcn_mfma_i32_16x16x64_i8(a1, b1, acc[1][1], 0, 0, 0);
    }
    short* Sb = g_S16 + (size_t)t * BHNN + (size_t)bh * Nn * Nn;
#pragma unroll
    for (int i = 0; i < 2; ++i)
#pragma unroll
        for (int j = 0; j < 2; ++j)
#pragma unroll
            for (int q = 0; q < 4; ++q) {
                int row = row0 + i * 16 + (lane >> 4) * 4 + q;
                int col = col0 + j * 16 + lr;
                Sb[row * Nn + col] = (short)acc[i][j][q];
            }
}

// ---------------- ALL-t aif IF + spiking softmax + sif IF (reg state) -------
__global__ __launch_bounds__(256) void attn_pipeline_all() {
    int rowid = blockIdx.x;                  // bh*512 + n
    size_t base = (size_t)rowid * Nn;
    int tid = threadIdx.x;
    __shared__ int   redI[4];
    __shared__ float redF[4];

    int   aq8[2]  = {4, 4};
    int   aac[2]  = {0, 0};
    float sq[2]   = {0.5f, 0.5f};
    int   sa[2]   = {0, 0};
    float yold[2] = {0.0f, 0.0f};

    for (int t = 0; t < Tn; ++t) {
        float st = (t + 1) < 6 ? (float)(t + 1) / 6.0f : 1.0f;
        const short* S = g_S16 + (size_t)t * BHNN;

        int X[2];
        int myMax = -128;
#pragma unroll
        for (int u = 0; u < 2; ++u) {
            int c = tid + u * 256;
            int s  = S[base + c];
            int q8 = aq8[u] + s;
            int a  = aac[u];
            bool pos = (q8 >= 8) && (a < 7);
            bool neg = (q8 < 0) && (a > -8);
            int o = pos ? 1 : (neg ? -1 : 0);
            aq8[u] = q8 - (o << 3);
            a += o;
            aac[u] = a;
            X[u] = a;
            myMax = max(myMax, a);
        }
        for (int off = 32; off; off >>= 1) myMax = max(myMax, __shfl_xor(myMax, off));
        if ((tid & 63) == 0) redI[tid >> 6] = myMax;
        __syncthreads();
        int M = max(max(redI[0], redI[1]), max(redI[2], redI[3]));

        float e[2];
        float mySum = 0.0f;
#pragma unroll
        for (int u = 0; u < 2; ++u) { e[u] = expf((float)(X[u] - M)); mySum += e[u]; }
        for (int off = 32; off; off >>= 1) mySum += __shfl_xor(mySum, off);
        if ((tid & 63) == 0) redF[tid >> 6] = mySum;
        __syncthreads();
        float Ssum = (redF[0] + redF[1]) + (redF[2] + redF[3]);

#pragma unroll
        for (int u = 0; u < 2; ++u) {
            int c = tid + u * 256;
            float y = (e[u] / Ssum) * st;
            float dlt = y - yold[u];
            yold[u] = y;
            float q = sq[u] + dlt;
            int a = sa[u];
            bool pos = ((q - 1.0f) >= 0.0f) && (a < 7);
            bool neg = (q < 0.0f) && (a > 0);
            float o = pos ? 1.0f : (neg ? -1.0f : 0.0f);
            sq[u] = q - o;
            a += (int)o;
            sa[u] = a;
            g_sifa8[(size_t)t * BHNN + base + c] = (int8_t)a;
            g_spk8[(size_t)t * BHNN + base + c]  = (int8_t)o;
        }
    }
}

// ------- PV (i8 MFMA, t-loop) + FUSED oif epilogue (reg state across t) -----
__global__ __launch_bounds__(256) void gemm_pv_oif_all() {
    int bh = blockIdx.y;
    int tm = blockIdx.x;
    int wave = threadIdx.x >> 6, lane = threadIdx.x & 63;
    int wr = wave >> 1, wc = wave & 1;
    int row0 = tm * 64 + wr * 32, col0 = wc * 32;
    int lr = lane & 15, kg = (lane >> 4) * 16;
    int b = bh / 12, h = bh - b * 12;

    float oq[2][2][4];
    int   oa[2][2][4];
#pragma unroll
    for (int i = 0; i < 2; ++i)
#pragma unroll
        for (int j = 0; j < 2; ++j)
#pragma unroll
            for (int q = 0; q < 4; ++q) { oq[i][j][q] = 0.5f; oa[i][j][q] = 0; }

    for (int t = 0; t < Tn; ++t) {
        const int8_t* Aa  = g_sifa8 + (size_t)t * BHNN + (size_t)bh * Nn * Nn;
        const int8_t* Asp = g_spk8  + (size_t)t * BHNN + (size_t)bh * Nn * Nn;
        const int8_t* Bb  = g_vT + ((size_t)t * BHn + bh) * Dn * 1024;
        i32x4 acc[2][2] = {};
        for (int kk = 0; kk < 512; kk += 64) {
            i32x4 a0 = *(const i32x4*)(Aa + (size_t)(row0 + lr) * 512 + kk + kg);
            i32x4 a1 = *(const i32x4*)(Aa + (size_t)(row0 + 16 + lr) * 512 + kk + kg);
            i32x4 b0 = *(const i32x4*)(Bb + (size_t)(col0 + lr) * 1024 + kk + kg);
            i32x4 b1 = *(const i32x4*)(Bb + (size_t)(col0 + 16 + lr) * 1024 + kk + kg);
            acc[0][0] = __builtin_amdgcn_mfma_i32_16x16x64_i8(a0, b0, acc[0][0], 0, 0, 0);
            acc[0][1] = __builtin_amdgcn_mfma_i32_16x16x64_i8(a0, b1, acc[0][1], 0, 0, 0);
            acc[1][0] = __builtin_amdgcn_mfma_i32_16x16x64_i8(a1, b0, acc[1][0], 0, 0, 0);
            acc[1][1] = __builtin_amdgcn_mfma_i32_16x16x64_i8(a1, b1, acc[1][1], 0, 0, 0);
        }
        for (int kk = 0; kk < 512; kk += 64) {
            i32x4 a0 = *(const i32x4*)(Asp + (size_t)(row0 + lr) * 512 + kk + kg);
            i32x4 a1 = *(const i32x4*)(Asp + (size_t)(row0 + 16 + lr) * 512 + kk + kg);
            i32x4 b0 = *(const i32x4*)(Bb + (size_t)(col0 + lr) * 1024 + 512 + kk + kg);
            i32x4 b1 = *(const i32x4*)(Bb + (size_t)(col0 + 16 + lr) * 1024 + 512 + kk + kg);
            acc[0][0] = __builtin_amdgcn_mfma_i32_16x16x64_i8(a0, b0, acc[0][0], 0, 0, 0);
            acc[0][1] = __builtin_amdgcn_mfma_i32_16x16x64_i8(a0, b1, acc[0][1], 0, 0, 0);
            acc[1][0] = __builtin_amdgcn_mfma_i32_16x16x64_i8(a1, b0, acc[1][0], 0, 0, 0);
            acc[1][1] = __builtin_amdgcn_mfma_i32_16x16x64_i8(a1, b1, acc[1][1], 0, 0, 0);
        }
        // fused oif epilogue (exact int -> f32, IF state in registers)
#pragma unroll
        for (int i = 0; i < 2; ++i)
#pragma unroll
            for (int j = 0; j < 2; ++j)
#pragma unroll
                for (int q = 0; q < 4; ++q) {
                    int row = row0 + i * 16 + (lane >> 4) * 4 + q;   // n
                    int col = col0 + j * 16 + lr;                    // d
                    float x = (float)acc[i][j][q];
                    float o = if_sym(x, oq[i][j][q], oa[i][j][q]);
                    size_t bn = (size_t)(b * Nn + row);
                    g_osp8i[(bn * 8 + t) * Cn + h * 64 + col] = (int8_t)o;
                }
    }
}

// ---------------- proj GEMM 128x128 (frozen fp32 chain, int8-A) + pif -------
__global__ __launch_bounds__(256) void gemm_proj_pif_all(
    const float* __restrict__ B, float* __restrict__ outp)
{
    __shared__ __align__(16) float As[16][132];
    __shared__ __align__(16) float Bs[16][132];
    const int tid = threadIdx.x;
    const int m0 = blockIdx.y * 128;
    const int j0 = blockIdx.x * 128;
    const int ty = tid >> 4, tx = tid & 15;

    float acc[8][8];
#pragma unroll
    for (int i = 0; i < 8; ++i)
#pragma unroll
        for (int j = 0; j < 8; ++j) acc[i][j] = 0.0f;

    for (int k0 = 0; k0 < Cn; k0 += 16) {
        {   // A staging: int8 spikes -> exact fp32
            int row = tid >> 1;
            int c8 = (tid & 1) * 8;
            s8x8 v = *(const s8x8*)(g_osp8i + (size_t)(m0 + row) * Cn + k0 + c8);
#pragma unroll
            for (int j = 0; j < 8; ++j) As[c8 + j][row] = (float)v[j];
        }
#pragma unroll
        for (int u = 0; u < 2; ++u) {
            int f = tid + u * 256;
            int row = f >> 2;
            int c4 = (f & 3) * 4;
            float4 bv = *(const float4*)(B + (size_t)(j0 + row) * Cn + k0 + c4);
            Bs[c4 + 0][row] = bv.x; Bs[c4 + 1][row] = bv.y;
            Bs[c4 + 2][row] = bv.z; Bs[c4 + 3][row] = bv.w;
        }
        __syncthreads();
#pragma unroll
        for (int k = 0; k < 16; ++k) {
            alignas(16) float a[8];
            alignas(16) float b[8];
            *(float4*)(a)     = *(const float4*)&As[k][ty * 8];
            *(float4*)(a + 4) = *(const float4*)&As[k][ty * 8 + 4];
            *(float4*)(b)     = *(const float4*)&Bs[k][tx * 8];
            *(float4*)(b + 4) = *(const float4*)&Bs[k][tx * 8 + 4];
#pragma unroll
            for (int i = 0; i < 8; ++i)
#pragma unroll
                for (int j = 0; j < 8; ++j)
                    acc[i][j] = fmaf(a[i], b[j], acc[i][j]);
        }
        __syncthreads();
    }

    // fused pif epilogue: 8 consecutive cols, chains over t=i, float4 stores
    const size_t bn = (size_t)((m0 + ty * 8) >> 3);
    const int col0 = j0 + tx * 8;
    float q[8]; int a[8];
#pragma unroll
    for (int j = 0; j < 8; ++j) { q[j] = 0.5f; a[j] = 0; }
#pragma unroll
    for (int t = 0; t < Tn; ++t) {
        alignas(16) float o[8];
#pragma unroll
        for (int j = 0; j < 8; ++j)
            o[j] = if_sym(acc[t][j], q[j], a[j]);
        float* op = outp + (size_t)t * BNC + bn * Cn + col0;
        *(float4*)(op)     = *(const float4*)(o);
        *(float4*)(op + 4) = *(const float4*)(o + 4);
    }
}

extern "C" void kernel_launch(void* const* d_in, const int* in_sizes, int n_in,
                              void* d_out, int out_size, void* d_ws, size_t ws_size,
                              hipStream_t stream) {
    (void)in_sizes; (void)n_in; (void)out_size; (void)d_ws; (void)ws_size;
    const float* x      = (const float*)d_in[0];
    const float* w_qkv  = (const float*)d_in[1];
    const float* w_proj = (const float*)d_in[2];
    float* outp = (float*)d_out;

    // qkv GEMM [32768 x 2304] K=768, tile 128x128, fused q/k/v IF epilogue
    gemm_qkv_fused<<<dim3(C3n / 128, (Tn * BNn) / 128), 256, 0, stream>>>(x, w_qkv);
    // transposed V operand
    vT_build<<<Tn * BHn, 256, 0, stream>>>();
    // all-t attn logits (i8 MFMA, exact)
    gemm_attn_all<<<dim3(64, BHn, Tn), 256, 0, stream>>>();
    // all-t aif + softmax + sif recurrence (reg state)
    attn_pipeline_all<<<BHn * Nn, 256, 0, stream>>>();
    // all-t PV (i8 MFMA) + fused oif
    gemm_pv_oif_all<<<dim3(8, BHn), 256, 0, stream>>>();
    // proj GEMM [32768 x 768] K=768, tile 128x128, fused pif -> output
    gemm_proj_pif_all<<<dim3(Cn / 128, (Tn * BNn) / 128), 256, 0, stream>>>(w_proj, outp);
}